// Round 1
// baseline (1746.335 us; speedup 1.0000x reference)
//
#include <hip/hip_runtime.h>
#include <stdint.h>

// Problem constants (maxdisp is structurally 48 per reference; d_in[9] is a
// device scalar we cannot read on host without breaking graph capture).
#define HH   160
#define WW   576
#define CIN  64
#define CMID 32
#define BATCH 8
#define MAXD 48

typedef unsigned int  uint;
typedef unsigned short ushort;

// ---------------- workspace layout (floats unless noted) ----------------
// wt   : [64*9][32] f32 @ 0            (BN-folded, transposed conv weights)
// bias1: [32]          @ 73728 B
// dwt  : [32][32] f32  @ 73856 B       (dwt[c*32+o] = desc_w[o][c])
// db   : [32]          @ 77952 B
// featL: [B][H][W][32] bf16 @ 131072 B (47,185,920 B)
// featR: same, following featL
static constexpr size_t WT_OFF  = 0;               // float index
static constexpr size_t B1_OFF  = 73728 / 4;
static constexpr size_t DWT_OFF = 73856 / 4;
static constexpr size_t B2_OFF  = 77952 / 4;
static constexpr size_t FEAT_OFF_BYTES = 131072;
static constexpr size_t FEAT_ELEMS = (size_t)BATCH * HH * WW * 32; // ushorts per side

__device__ __forceinline__ ushort f2bf(float f) {
    uint u = __float_as_uint(f);
    u = (u + 0x7fffu + ((u >> 16) & 1u)) >> 16;   // RNE
    return (ushort)u;
}
__device__ __forceinline__ float bf2f_lo(uint u) { return __uint_as_float(u << 16); }
__device__ __forceinline__ float bf2f_hi(uint u) { return __uint_as_float(u & 0xffff0000u); }

// ---------------- kernel 0: fold BN, transpose weights ----------------
__global__ void prep_kernel(const float* __restrict__ conv_w,
                            const float* __restrict__ gamma,
                            const float* __restrict__ beta,
                            const float* __restrict__ mean,
                            const float* __restrict__ var,
                            const float* __restrict__ desc_w,
                            const float* __restrict__ desc_b,
                            float* __restrict__ ws) {
    int tid = blockIdx.x * 256 + threadIdx.x;
    if (tid < CIN * 9 * CMID) {                 // 18432
        int c    = tid & 31;
        int rest = tid >> 5;                    // 0..575
        int k    = rest % 9;
        int ci   = rest / 9;
        float inv = gamma[c] * rsqrtf(var[c] + 1e-5f);
        ws[WT_OFF + (size_t)((ci * 9 + k) << 5) + c] =
            conv_w[(size_t)(c * CIN + ci) * 9 + k] * inv;
    }
    if (tid < CMID * CMID) {                    // 1024
        int c = tid >> 5, o = tid & 31;
        ws[DWT_OFF + tid] = desc_w[o * CMID + c];
    }
    if (tid < CMID) {
        float inv = gamma[tid] * rsqrtf(var[tid] + 1e-5f);
        ws[B1_OFF + tid] = beta[tid] - mean[tid] * inv;
        ws[B2_OFF + tid] = desc_b[tid];
    }
}

// ---------------- kernel 1: conv3x3 + BN + ReLU + 1x1, bf16 features ----------------
#define WTILE 192
__global__ __launch_bounds__(WTILE)
void feat_kernel(const float* __restrict__ left,
                 const float* __restrict__ right,
                 const float* __restrict__ ws,
                 ushort* __restrict__ featL,
                 ushort* __restrict__ featR) {
    __shared__ float in_lds[16][3][194];        // 37,248 B

    const int tw = threadIdx.x;                 // 0..191 -> output column within tile
    const int w0 = blockIdx.x * WTILE;          // 0,192,384
    const int h  = blockIdx.y;
    const int z  = blockIdx.z;                  // 0..7 left, 8..15 right
    const int b  = z & 7;
    const float* __restrict__ in = (z < 8 ? left : right) + (size_t)b * CIN * HH * WW;
    ushort* __restrict__ feat = (z < 8 ? featL : featR);

    const float* __restrict__ wt = ws + WT_OFF;

    float acc[32];
#pragma unroll
    for (int c = 0; c < 32; ++c) acc[c] = 0.f;

    for (int ci0 = 0; ci0 < CIN; ci0 += 16) {
        // cooperative load of a 16ci x 3row x 194col input tile (zero-padded)
        for (int idx = tw; idx < 16 * 3 * 194; idx += WTILE) {
            int ci  = idx / (3 * 194);
            int rem = idx - ci * (3 * 194);
            int r   = rem / 194;
            int col = rem - r * 194;
            int gh = h + r - 1;
            int gw = w0 + col - 1;
            float v = 0.f;
            if ((unsigned)gh < HH && (unsigned)gw < WW)
                v = in[((size_t)(ci0 + ci) * HH + gh) * WW + gw];
            in_lds[ci][r][col] = v;
        }
        __syncthreads();

#pragma unroll 2
        for (int ci = 0; ci < 16; ++ci) {
            float xv[9];
#pragma unroll
            for (int r = 0; r < 3; ++r)
#pragma unroll
                for (int kw = 0; kw < 3; ++kw)
                    xv[r * 3 + kw] = in_lds[ci][r][tw + kw];
            const float* __restrict__ wrow = wt + (size_t)((ci0 + ci) * 9) * 32;
#pragma unroll
            for (int k = 0; k < 9; ++k) {
                float x = xv[k];
                const float* __restrict__ wr = wrow + k * 32;  // wave-uniform -> s_load
#pragma unroll
                for (int c = 0; c < 32; ++c)
                    acc[c] = fmaf(x, wr[c], acc[c]);
            }
        }
        __syncthreads();
    }

    // BN bias + ReLU
    const float* __restrict__ b1 = ws + B1_OFF;
    float y[32];
#pragma unroll
    for (int c = 0; c < 32; ++c) y[c] = fmaxf(acc[c] + b1[c], 0.f);

    // 1x1 conv (desc)
    const float* __restrict__ dwt = ws + DWT_OFF;
    const float* __restrict__ b2  = ws + B2_OFF;
    float z2[32];
#pragma unroll
    for (int o = 0; o < 32; ++o) z2[o] = b2[o];
#pragma unroll
    for (int c = 0; c < 32; ++c) {
        float x = y[c];
        const float* __restrict__ dr = dwt + c * 32;           // wave-uniform
#pragma unroll
        for (int o = 0; o < 32; ++o) z2[o] = fmaf(x, dr[o], z2[o]);
    }

    // store 32 channels as bf16, [b][h][w][c] layout, 64 B per pixel
    size_t pix = ((size_t)b * HH + h) * WW + (w0 + tw);
    uint out_u[16];
#pragma unroll
    for (int i = 0; i < 16; ++i)
        out_u[i] = (uint)f2bf(z2[2 * i]) | ((uint)f2bf(z2[2 * i + 1]) << 16);
    uint4* dst = (uint4*)(feat + pix * 32);
#pragma unroll
    for (int i = 0; i < 4; ++i) dst[i] = ((uint4*)out_u)[i];
}

// ---------------- kernel 2: 48-disparity correlation cost volume ----------------
__global__ __launch_bounds__(WTILE)
void cv_kernel(const ushort* __restrict__ featL,
               const ushort* __restrict__ featR,
               float* __restrict__ out) {
    // R row staged with 80 B (=40 ushort) stride per pixel: 80*l mod 128 covers
    // all eight 16B slots -> conflict-free ds_read_b128 at lane-stride-1 w.
    __shared__ ushort r_lds[WW * 40];           // 46,080 B

    const int t  = threadIdx.x;                 // 0..191
    const int bh = blockIdx.x;                  // b*160 + h
    const int b  = bh / HH;
    const int h  = bh - b * HH;
    const ushort* __restrict__ Lrow = featL + ((size_t)b * HH + h) * WW * 32;
    const ushort* __restrict__ Rrow = featR + ((size_t)b * HH + h) * WW * 32;

    // stage R into LDS (swizzled stride 40)
#pragma unroll
    for (int k = 0; k < 3; ++k) {
        int w = t + k * WTILE;
        const uint4* src = (const uint4*)(Rrow + (size_t)w * 32);
        uint4* dst = (uint4*)(r_lds + (size_t)w * 40);
#pragma unroll
        for (int j = 0; j < 4; ++j) dst[j] = src[j];
    }

    // L for this thread's 3 pixels -> f32 registers (96 VGPR)
    float Lf[3][32];
#pragma unroll
    for (int k = 0; k < 3; ++k) {
        int w = t + k * WTILE;
        const uint4* src = (const uint4*)(Lrow + (size_t)w * 32);
#pragma unroll
        for (int j = 0; j < 4; ++j) {
            uint4 v = src[j];
            uint vv[4] = {v.x, v.y, v.z, v.w};
#pragma unroll
            for (int q = 0; q < 4; ++q) {
                Lf[k][j * 8 + q * 2]     = bf2f_lo(vv[q]);
                Lf[k][j * 8 + q * 2 + 1] = bf2f_hi(vv[q]);
            }
        }
    }
    __syncthreads();

    float* __restrict__ outBase = out + ((size_t)b * MAXD * HH + h) * WW;
    for (int d = 0; d < MAXD; ++d) {
#pragma unroll
        for (int k = 0; k < 3; ++k) {
            int w = t + k * WTILE;
            float res = 0.f;
            if (w >= d) {
                const uint4* rp = (const uint4*)(r_lds + (size_t)(w - d) * 40);
                float s0 = 0.f, s1 = 0.f;
#pragma unroll
                for (int j = 0; j < 4; ++j) {
                    uint4 v = rp[j];
                    uint vv[4] = {v.x, v.y, v.z, v.w};
#pragma unroll
                    for (int q = 0; q < 4; ++q) {
                        int idx = j * 8 + q * 2;
                        s0 = fmaf(Lf[k][idx],     bf2f_lo(vv[q]), s0);
                        s1 = fmaf(Lf[k][idx + 1], bf2f_hi(vv[q]), s1);
                    }
                }
                res = (s0 + s1) * (1.f / 32.f);
            }
            outBase[(size_t)d * HH * WW + w] = res;
        }
    }
}

// ---------------- launch ----------------
extern "C" void kernel_launch(void* const* d_in, const int* in_sizes, int n_in,
                              void* d_out, int out_size, void* d_ws, size_t ws_size,
                              hipStream_t stream) {
    const float* left   = (const float*)d_in[0];
    const float* right  = (const float*)d_in[1];
    const float* conv_w = (const float*)d_in[2];
    const float* gamma  = (const float*)d_in[3];
    const float* beta   = (const float*)d_in[4];
    const float* mean   = (const float*)d_in[5];
    const float* var    = (const float*)d_in[6];
    const float* desc_w = (const float*)d_in[7];
    const float* desc_b = (const float*)d_in[8];
    float*  out   = (float*)d_out;
    float*  ws    = (float*)d_ws;
    ushort* featL = (ushort*)((char*)d_ws + FEAT_OFF_BYTES);
    ushort* featR = featL + FEAT_ELEMS;

    prep_kernel<<<72, 256, 0, stream>>>(conv_w, gamma, beta, mean, var, desc_w, desc_b, ws);
    feat_kernel<<<dim3(WW / WTILE, HH, 2 * BATCH), WTILE, 0, stream>>>(left, right, ws, featL, featR);
    cv_kernel<<<dim3(BATCH * HH), WTILE, 0, stream>>>(featL, featR, out);
}

// Round 2
// 415.453 us; speedup vs baseline: 4.2034x; 4.2034x over previous
//
#include <hip/hip_runtime.h>
#include <stdint.h>

#define HH   160
#define WW   576
#define CIN  64
#define BATCH 8
#define MAXD 48

typedef unsigned int  uint;
typedef unsigned short ushort;
typedef __attribute__((ext_vector_type(8))) short bf16x8;
typedef __attribute__((ext_vector_type(4))) float f32x4;

// ---------------- workspace layout (bytes) ----------------
// WtA  : ushort[32*9*64] @ 0      (BN-folded conv weights, [ch][tap][ci] bf16)
// DwtP : ushort[32*32]   @ 36864  (desc weights, k-permuted to C-frag order)
// b1   : float[32]       @ 38912  (BN bias)
// b2   : float[32]       @ 39040  (desc bias)
// featL: ushort[B*H*W*32]@ 40960  (bf16 NHWC features), featR follows
static constexpr size_t WTA_OFF  = 0;
static constexpr size_t DWT_OFF  = 36864;
static constexpr size_t B1_OFF   = 38912;
static constexpr size_t B2_OFF   = 39040;
static constexpr size_t FEAT_OFF = 40960;
static constexpr size_t FEAT_ELEMS = (size_t)BATCH * HH * WW * 32;

__device__ __forceinline__ uint f2bf(float f) {
    uint u = __float_as_uint(f);
    u = (u + 0x7fffu + ((u >> 16) & 1u)) >> 16;   // RNE
    return u;
}
__device__ __forceinline__ float bf2f_lo(uint u) { return __uint_as_float(u << 16); }
__device__ __forceinline__ float bf2f_hi(uint u) { return __uint_as_float(u & 0xffff0000u); }

// ---------------- kernel 0: fold BN, build bf16 weight layouts ----------------
__global__ void prep_kernel(const float* __restrict__ conv_w,
                            const float* __restrict__ gamma,
                            const float* __restrict__ beta,
                            const float* __restrict__ mean,
                            const float* __restrict__ var,
                            const float* __restrict__ desc_w,
                            const float* __restrict__ desc_b,
                            char* __restrict__ ws) {
    int tid = blockIdx.x * 256 + threadIdx.x;
    ushort* wtA = (ushort*)(ws + WTA_OFF);
    ushort* dwt = (ushort*)(ws + DWT_OFF);
    float*  b1  = (float*)(ws + B1_OFF);
    float*  b2  = (float*)(ws + B2_OFF);
    if (tid < 32 * 9 * 64) {               // WtA[(ch*9+tap)*64+ci] == index tid
        int ci = tid & 63;
        int r2 = tid >> 6;                 // ch*9 + tap
        int tap = r2 % 9;
        int ch  = r2 / 9;
        float inv = gamma[ch] * rsqrtf(var[ch] + 1e-5f);
        wtA[tid] = (ushort)f2bf(conv_w[(size_t)(ch * 64 + ci) * 9 + tap] * inv);
    }
    if (tid < 1024) {                      // DwtP[o][p]: p=8g+j holds desc_w[o][4g+(j&3)+16*(j>>2)]
        int o = tid >> 5, p = tid & 31;
        int g = p >> 3, j = p & 7;
        int mid = 4 * g + (j & 3) + 16 * ((j >> 2) & 1);
        dwt[tid] = (ushort)f2bf(desc_w[o * 32 + mid]);
    }
    if (tid < 32) {
        float inv = gamma[tid] * rsqrtf(var[tid] + 1e-5f);
        b1[tid] = beta[tid] - mean[tid] * inv;
        b2[tid] = desc_b[tid];
    }
}

// ---------------- kernel 1: MFMA conv3x3 + BN + ReLU + 1x1, bf16 NHWC feats ----------------
#define TW 96
#define NX 6          // 576/96
#define NWG (NX * HH * 2 * BATCH)   // 15360
__global__ __launch_bounds__(192)
void feat_mfma(const float* __restrict__ left,
               const float* __restrict__ right,
               const char* __restrict__ ws,
               ushort* __restrict__ featL,
               ushort* __restrict__ featR) {
    // [3 rows][98 cols][64 ci] bf16, 144 B per pixel (72 ushorts: 64 data + 8 pad)
    __shared__ __align__(16) ushort tile[3 * 98 * 72];   // 42,336 B -> 3 blocks/CU

    // bijective XCD swizzle: NWG = 8 * 1920; each XCD gets 2 complete images,
    // x-fastest then h order -> 3-row halo is L2-resident.
    int bid = blockIdx.x;
    int nid = (bid & 7) * (NWG / 8) + (bid >> 3);
    int x = nid % NX;
    int rest = nid / NX;
    int h = rest % HH;
    int z = rest / HH;                       // 0..7 left, 8..15 right
    int b = z & 7;
    const float* __restrict__ in = (z < 8 ? left : right) + (size_t)b * CIN * HH * WW;
    ushort* __restrict__ feat = (z < 8 ? featL : featR);
    int w0 = x * TW;

    // ---- stage input tile (f32 NCHW -> bf16 [r][col][ci] LDS) ----
    for (int t = threadIdx.x; t < 98 * 24; t += 192) {
        int col = t % 98;                    // lanes vary col -> coalesced global reads
        int r2  = t / 98;                    // 0..23
        int cib = r2 & 7;                    // 8-ci block
        int r   = r2 >> 3;                   // 0..2
        int gh = h + r - 1;
        int gw = w0 + col - 1;
        uint pk0 = 0, pk1 = 0, pk2 = 0, pk3 = 0;
        if ((unsigned)gh < HH && (unsigned)gw < WW) {
            const float* src = in + ((size_t)(cib * 8) * HH + gh) * WW + gw;
            const size_t PL = (size_t)HH * WW;
            pk0 = f2bf(src[0])      | (f2bf(src[PL])     << 16);
            pk1 = f2bf(src[2 * PL]) | (f2bf(src[3 * PL]) << 16);
            pk2 = f2bf(src[4 * PL]) | (f2bf(src[5 * PL]) << 16);
            pk3 = f2bf(src[6 * PL]) | (f2bf(src[7 * PL]) << 16);
        }
        *(uint4*)&tile[(r * 98 + col) * 72 + cib * 8] = make_uint4(pk0, pk1, pk2, pk3);
    }
    __syncthreads();

    const int lane = threadIdx.x & 63;
    const int wv   = threadIdx.x >> 6;       // 0..2, 32 pixels each
    const int ln   = lane & 15;              // pixel within n-tile / ch row
    const int g    = lane >> 4;              // k-group 0..3

    const ushort* __restrict__ wtA = (const ushort*)(ws + WTA_OFF);
    const ushort* aBase = wtA + ln * 576 + g * 8;   // + mt*9216 + tap*64 + kk*32

    f32x4 acc[2][2] = {};                    // [mt(ch16)][nt(pix16)]

#pragma unroll
    for (int tap = 0; tap < 9; ++tap) {
        const int r = tap / 3, kw = tap % 3;
        bf16x8 a0k0 = *(const bf16x8*)(aBase + tap * 64);
        bf16x8 a0k1 = *(const bf16x8*)(aBase + tap * 64 + 32);
        bf16x8 a1k0 = *(const bf16x8*)(aBase + 9216 + tap * 64);
        bf16x8 a1k1 = *(const bf16x8*)(aBase + 9216 + tap * 64 + 32);
#pragma unroll
        for (int kk = 0; kk < 2; ++kk) {
            bf16x8 bb0 = *(const bf16x8*)&tile[(r * 98 + wv * 32 + 0  + ln + kw) * 72 + kk * 32 + g * 8];
            bf16x8 bb1 = *(const bf16x8*)&tile[(r * 98 + wv * 32 + 16 + ln + kw) * 72 + kk * 32 + g * 8];
            bf16x8 a0 = kk ? a0k1 : a0k0;
            bf16x8 a1 = kk ? a1k1 : a1k0;
            acc[0][0] = __builtin_amdgcn_mfma_f32_16x16x32_bf16(a0, bb0, acc[0][0], 0, 0, 0);
            acc[0][1] = __builtin_amdgcn_mfma_f32_16x16x32_bf16(a0, bb1, acc[0][1], 0, 0, 0);
            acc[1][0] = __builtin_amdgcn_mfma_f32_16x16x32_bf16(a1, bb0, acc[1][0], 0, 0, 0);
            acc[1][1] = __builtin_amdgcn_mfma_f32_16x16x32_bf16(a1, bb1, acc[1][1], 0, 0, 0);
        }
    }

    // ---- BN bias + ReLU, pack P-fragments in C-layout order (mid = 4g+(j&3)+16*(j>>2)) ----
    const float* __restrict__ b1 = (const float*)(ws + B1_OFF);
    const float* __restrict__ b2 = (const float*)(ws + B2_OFF);
    f32x4 b1v0 = *(const f32x4*)(b1 + g * 4);
    f32x4 b1v1 = *(const f32x4*)(b1 + 16 + g * 4);
    bf16x8 p[2];
#pragma unroll
    for (int nt = 0; nt < 2; ++nt) {
#pragma unroll
        for (int j = 0; j < 8; ++j) {
            float v = acc[j >> 2][nt][j & 3] + ((j >> 2) ? b1v1[j & 3] : b1v0[j & 3]);
            v = fmaxf(v, 0.f);
            p[nt][j] = (short)f2bf(v);
        }
    }

    // ---- 1x1 desc conv: DwtP (k-permuted to match) x P, bias-initialized acc ----
    const ushort* __restrict__ dwt = (const ushort*)(ws + DWT_OFF);
    const ushort* dBase = dwt + ln * 32 + g * 8;
    bf16x8 da0 = *(const bf16x8*)(dBase);
    bf16x8 da1 = *(const bf16x8*)(dBase + 512);
    f32x4 b2v0 = *(const f32x4*)(b2 + g * 4);
    f32x4 b2v1 = *(const f32x4*)(b2 + 16 + g * 4);
    f32x4 acc2[2][2];
#pragma unroll
    for (int nt = 0; nt < 2; ++nt) { acc2[0][nt] = b2v0; acc2[1][nt] = b2v1; }
#pragma unroll
    for (int nt = 0; nt < 2; ++nt) {
        acc2[0][nt] = __builtin_amdgcn_mfma_f32_16x16x32_bf16(da0, p[nt], acc2[0][nt], 0, 0, 0);
        acc2[1][nt] = __builtin_amdgcn_mfma_f32_16x16x32_bf16(da1, p[nt], acc2[1][nt], 0, 0, 0);
    }

    // ---- store features bf16 NHWC: ch = 16*mt2 + 4g + reg ----
    size_t pixBase = ((size_t)b * HH + h) * WW + w0 + wv * 32 + ln;
#pragma unroll
    for (int nt = 0; nt < 2; ++nt) {
#pragma unroll
        for (int mt2 = 0; mt2 < 2; ++mt2) {
            uint u0 = f2bf(acc2[mt2][nt][0]) | (f2bf(acc2[mt2][nt][1]) << 16);
            uint u1 = f2bf(acc2[mt2][nt][2]) | (f2bf(acc2[mt2][nt][3]) << 16);
            *(uint2*)(feat + (pixBase + nt * 16) * 32 + mt2 * 16 + g * 4) = make_uint2(u0, u1);
        }
    }
}

// ---------------- kernel 2: 48-disparity correlation cost volume ----------------
#define CVT 192
__global__ __launch_bounds__(CVT)
void cv_kernel(const ushort* __restrict__ featL,
               const ushort* __restrict__ featR,
               float* __restrict__ out) {
    // R row staged with 80 B (=40 ushort) stride per pixel: 80*l mod 128 covers
    // all eight 16B slots -> conflict-free ds_read_b128 at lane-stride-1 w.
    __shared__ ushort r_lds[WW * 40];           // 46,080 B

    const int t  = threadIdx.x;                 // 0..191
    const int bh = blockIdx.x;                  // b*160 + h
    const int b  = bh / HH;
    const int h  = bh - b * HH;
    const ushort* __restrict__ Lrow = featL + ((size_t)b * HH + h) * WW * 32;
    const ushort* __restrict__ Rrow = featR + ((size_t)b * HH + h) * WW * 32;

#pragma unroll
    for (int k = 0; k < 3; ++k) {
        int w = t + k * CVT;
        const uint4* src = (const uint4*)(Rrow + (size_t)w * 32);
        uint4* dst = (uint4*)(r_lds + (size_t)w * 40);
#pragma unroll
        for (int j = 0; j < 4; ++j) dst[j] = src[j];
    }

    float Lf[3][32];
#pragma unroll
    for (int k = 0; k < 3; ++k) {
        int w = t + k * CVT;
        const uint4* src = (const uint4*)(Lrow + (size_t)w * 32);
#pragma unroll
        for (int j = 0; j < 4; ++j) {
            uint4 v = src[j];
            uint vv[4] = {v.x, v.y, v.z, v.w};
#pragma unroll
            for (int q = 0; q < 4; ++q) {
                Lf[k][j * 8 + q * 2]     = bf2f_lo(vv[q]);
                Lf[k][j * 8 + q * 2 + 1] = bf2f_hi(vv[q]);
            }
        }
    }
    __syncthreads();

    float* __restrict__ outBase = out + ((size_t)b * MAXD * HH + h) * WW;
    for (int d = 0; d < MAXD; ++d) {
#pragma unroll
        for (int k = 0; k < 3; ++k) {
            int w = t + k * CVT;
            float res = 0.f;
            if (w >= d) {
                const uint4* rp = (const uint4*)(r_lds + (size_t)(w - d) * 40);
                float s0 = 0.f, s1 = 0.f;
#pragma unroll
                for (int j = 0; j < 4; ++j) {
                    uint4 v = rp[j];
                    uint vv[4] = {v.x, v.y, v.z, v.w};
#pragma unroll
                    for (int q = 0; q < 4; ++q) {
                        int idx = j * 8 + q * 2;
                        s0 = fmaf(Lf[k][idx],     bf2f_lo(vv[q]), s0);
                        s1 = fmaf(Lf[k][idx + 1], bf2f_hi(vv[q]), s1);
                    }
                }
                res = (s0 + s1) * (1.f / 32.f);
            }
            outBase[(size_t)d * HH * WW + w] = res;
        }
    }
}

// ---------------- launch ----------------
extern "C" void kernel_launch(void* const* d_in, const int* in_sizes, int n_in,
                              void* d_out, int out_size, void* d_ws, size_t ws_size,
                              hipStream_t stream) {
    const float* left   = (const float*)d_in[0];
    const float* right  = (const float*)d_in[1];
    const float* conv_w = (const float*)d_in[2];
    const float* gamma  = (const float*)d_in[3];
    const float* beta   = (const float*)d_in[4];
    const float* mean   = (const float*)d_in[5];
    const float* var    = (const float*)d_in[6];
    const float* desc_w = (const float*)d_in[7];
    const float* desc_b = (const float*)d_in[8];
    float*  out   = (float*)d_out;
    char*   ws    = (char*)d_ws;
    ushort* featL = (ushort*)(ws + FEAT_OFF);
    ushort* featR = featL + FEAT_ELEMS;

    prep_kernel<<<72, 256, 0, stream>>>(conv_w, gamma, beta, mean, var, desc_w, desc_b, ws);
    feat_mfma<<<NWG, 192, 0, stream>>>(left, right, ws, featL, featR);
    cv_kernel<<<BATCH * HH, CVT, 0, stream>>>(featL, featR, out);
}